// Round 1
// baseline (250.929 us; speedup 1.0000x reference)
//
#include <hip/hip_runtime.h>

#define N_SEQ 2048
#define S_LEN 4096
#define W_SEQ 64                               // u64 words per sequence (S/64)
#define TILE 64
#define T_TILES (N_SEQ / TILE)                 // 32
#define NBLK (T_TILES * (T_TILES + 1) / 2)     // 528 upper-triangle tiles
#define CHUNK 16                               // words per LDS K-chunk
#define STRIDE 17                              // padded LDS row stride (odd -> conflict-free)

// ---------------- Kernel 1: one-hot fp32 -> 2-bit packed bit-planes ----------------
// thread = one site; wave (64 lanes) = one u64 word per plane via __ballot.
__global__ __launch_bounds__(256) void encode_kernel(const float4* __restrict__ data,
                                                     ulonglong2* __restrict__ codes) {
    int t = blockIdx.x * 256 + threadIdx.x;            // t = i*S + s (flat site index)
    float4 v = data[t];                                // one-hot over A=4, 16B coalesced
    int c = (int)(v.y + 2.0f * v.z + 3.0f * v.w + 0.5f);   // exact token recovery
    unsigned long long lo = __ballot(c & 1);
    unsigned long long hi = __ballot(c & 2);
    if ((threadIdx.x & 63) == 0) {
        ulonglong2 e; e.x = lo; e.y = hi;
        codes[t >> 6] = e;
    }
}

// ---------------- Kernel 2: normalize embedding table (tiny: N x 2) ----------------
__global__ void zprep_kernel(const float* __restrict__ table, float4* __restrict__ zbuf) {
    int i = blockIdx.x * blockDim.x + threadIdx.x;
    if (i >= N_SEQ) return;
    float vx = table[2 * i], vy = table[2 * i + 1];
    float n = sqrtf(vx * vx + vy * vy);
    float f = tanhf(n) / fmaxf(n, 1e-12f);
    float zx = vx * f, zy = vy * f;
    float omn = 1.0f - (zx * zx + zy * zy);            // 1 - ||z||^2
    zbuf[i] = make_float4(zx, zy, omn, 0.0f);
}

// ---------------- Kernel 3: pairwise popcount-hamming + hyperbolic + reduce --------
// 64x64 pair tile per block; 16x16 threads, each owns 4x4 pairs (rows ty+16k, cols tx+16l).
// LDS stride 17 (odd): A-reads = 4 distinct bank-quads (free), B-reads 2-way (free, m136).
__global__ __launch_bounds__(256) void pairs_kernel(const ulonglong2* __restrict__ codes,
                                                    const float4* __restrict__ zbuf,
                                                    const float* __restrict__ log_scale,
                                                    double* __restrict__ partials) {
    __shared__ ulonglong2 As[TILE * STRIDE];
    __shared__ ulonglong2 Bs[TILE * STRIDE];
    __shared__ float wsum[4];

    int b = blockIdx.x;
    // triangle mapping: b = r*(r+1)/2 + c, with c <= r  (i-tile = c, j-tile = r, so i <= j)
    int r = (int)((sqrtf(8.0f * (float)b + 1.0f) - 1.0f) * 0.5f);
    while ((r + 1) * (r + 2) / 2 <= b) ++r;
    while (r * (r + 1) / 2 > b) --r;
    int c = b - r * (r + 1) / 2;
    int i0 = c * TILE, j0 = r * TILE;

    int tid = threadIdx.x;
    int tx = tid & 15, ty = tid >> 4;

    int mis[4][4];
#pragma unroll
    for (int k = 0; k < 4; ++k)
#pragma unroll
        for (int l = 0; l < 4; ++l) mis[k][l] = 0;

    for (int cc = 0; cc < W_SEQ / CHUNK; ++cc) {
        // stage 64 rows x 16 words per side; coalesced 16B global loads
#pragma unroll
        for (int p = 0; p < 4; ++p) {
            int e = tid + p * 256;                     // 0..1023
            int row = e >> 4, w = e & 15;
            As[row * STRIDE + w] = codes[(i0 + row) * W_SEQ + cc * CHUNK + w];
            Bs[row * STRIDE + w] = codes[(j0 + row) * W_SEQ + cc * CHUNK + w];
        }
        __syncthreads();
#pragma unroll
        for (int w = 0; w < CHUNK; ++w) {
            ulonglong2 a[4], bb[4];
#pragma unroll
            for (int k = 0; k < 4; ++k) a[k] = As[(ty + 16 * k) * STRIDE + w];
#pragma unroll
            for (int l = 0; l < 4; ++l) bb[l] = Bs[(tx + 16 * l) * STRIDE + w];
#pragma unroll
            for (int k = 0; k < 4; ++k)
#pragma unroll
                for (int l = 0; l < 4; ++l)
                    mis[k][l] += __popcll((a[k].x ^ bb[l].x) | (a[k].y ^ bb[l].y));
        }
        __syncthreads();
    }

    // fused epilogue: hamming = mis/S (exact), hyperbolic dist, weighted squared diff
    float scale = expf(log_scale[0]);
    const float inv_s = 1.0f / (float)S_LEN;
    float local = 0.0f;
#pragma unroll
    for (int k = 0; k < 4; ++k) {
        int i = i0 + ty + 16 * k;
        float4 zi = zbuf[i];
#pragma unroll
        for (int l = 0; l < 4; ++l) {
            int j = j0 + tx + 16 * l;
            float4 zj = zbuf[j];
            float ham = (float)mis[k][l] * inv_s;
            float dx = zi.x - zj.x, dy = zi.y - zj.y;
            float dsq = dx * dx + dy * dy;
            float arg = 1.0f + 2.0f * dsq / (zi.z * zj.z);
            arg = fmaxf(arg, 1.0f + 1e-7f);
            float dist = acoshf(arg) * scale;
            float d = ham - dist;
            float wgt = (i < j) ? 2.0f : (i == j ? 1.0f : 0.0f);  // symmetry weighting
            local += wgt * d * d;
        }
    }

    // block reduction -> one double partial per block (deterministic, no atomics)
#pragma unroll
    for (int off = 32; off > 0; off >>= 1) local += __shfl_down(local, off);
    if ((tid & 63) == 0) wsum[tid >> 6] = local;
    __syncthreads();
    if (tid == 0)
        partials[blockIdx.x] = (double)(wsum[0] + wsum[1] + wsum[2] + wsum[3]);
}

// ---------------- Kernel 4: final reduce of 528 partials -> scalar mean ----------------
__global__ void finalize_kernel(const double* __restrict__ partials, float* __restrict__ out) {
    __shared__ double ws[4];
    int tid = threadIdx.x;
    double s = 0.0;
    for (int k = tid; k < NBLK; k += 256) s += partials[k];
#pragma unroll
    for (int off = 32; off > 0; off >>= 1) s += __shfl_down(s, off);
    if ((tid & 63) == 0) ws[tid >> 6] = s;
    __syncthreads();
    if (tid == 0) {
        double tot = ws[0] + ws[1] + ws[2] + ws[3];
        out[0] = (float)(tot / ((double)N_SEQ * (double)N_SEQ));
    }
}

extern "C" void kernel_launch(void* const* d_in, const int* in_sizes, int n_in,
                              void* d_out, int out_size, void* d_ws, size_t ws_size,
                              hipStream_t stream) {
    const float4* data      = (const float4*)d_in[0];  // N x S x A fp32 one-hot
    const float*  table     = (const float*)d_in[1];   // N x 2
    const float*  log_scale = (const float*)d_in[2];   // scalar
    float* out = (float*)d_out;

    char* ws = (char*)d_ws;
    ulonglong2* codes    = (ulonglong2*)ws;                                  // 2 MB
    float4*     zbuf     = (float4*)(ws + (size_t)N_SEQ * W_SEQ * sizeof(ulonglong2));
    double*     partials = (double*)((char*)zbuf + (size_t)N_SEQ * sizeof(float4));

    encode_kernel  <<<N_SEQ * S_LEN / 256, 256, 0, stream>>>(data, codes);
    zprep_kernel   <<<(N_SEQ + 255) / 256, 256, 0, stream>>>(table, zbuf);
    pairs_kernel   <<<NBLK, 256, 0, stream>>>(codes, zbuf, log_scale, partials);
    finalize_kernel<<<1, 256, 0, stream>>>(partials, out);
}